// Round 3
// baseline (332.091 us; speedup 1.0000x reference)
//
#include <hip/hip_runtime.h>
#include <hip/hip_bf16.h>

// Problem: B=16, N=4096, D=768, M=8
//   xn = LayerNorm(x) * gamma + beta          [B,N,D]
//   sim = (queries @ xn^T) * D^-0.5           [B,M,N]
//   attn = softmax(sim, axis=-1)
//   out = attn @ xn                           [B,M,D]
// All I/O fp32. Compute fp32.
//
// Round-3: LDS-pipe diet on both hot loops.
//  - k_ln_sim: 2 rows per iteration -> qg ds_read_b128 halved (24->12/row);
//    1024 blocks x 4 waves x 8 pairs = exactly 65536 rows (no tail).
//  - k_stats: additionally materializes w[bm][n] = attn*rstd into ws.
//  - k_out: no LDS, no exp; w read at block-uniform addresses (scalar-load
//    eligible -> SGPR-operand FMAs); grid (16,3,32) = 6 blocks/CU.

#define B_ 16
#define N_ 4096
#define D_ 768
#define M_ 8
#define EPS_ 1e-3f
#define SCALE_ 0.03608439182435161f  // 768^-0.5

// ws layout (floats)
#define SIM_OFF   0            // B*M*N = 524288 floats
#define MEAN_OFF  524288       // B*N   =  65536
#define RSTD_OFF  589824       // B*N   =  65536
#define WBUF_OFF  655360       // B*M*N = 524288 floats (attn*rstd)

// ---------------- kernel 1: LayerNorm stats + sim = q . xn ----------------
// one wave per row-PAIR; lane owns 12 cols (3 float4) of each row.
// gamma folded into q: sim_m = SCALE*(rs*(dot(qg,v) - mu*qgs_m) + qb_m)
// qg table in LDS (block-shared); each qg fragment read once per 2 rows.
__global__ __launch_bounds__(256) void k_ln_sim(
    const float* __restrict__ x,
    const float* __restrict__ q,
    const float* __restrict__ gm,
    const float* __restrict__ bt,
    float* __restrict__ sim, float* __restrict__ meanb, float* __restrict__ rstdb)
{
    __shared__ __align__(16) float qg_s[8][768];   // 24 KB
    __shared__ float qgs_s[8], qb_s[8];

    const int lane = threadIdx.x & 63;
    const int wv   = threadIdx.x >> 6;             // 0..3

    // ---- init: wave wv prepares m0=2wv, m1=2wv+1
    {
        const int m0 = wv * 2, m1 = m0 + 1;
        float qgs0 = 0.f, qb0 = 0.f, qgs1 = 0.f, qb1 = 0.f;
#pragma unroll
        for (int i = 0; i < 3; i++) {
            const int c4 = (lane + i * 64) * 4;
            const float4 gv = *(const float4*)(gm + c4);
            const float4 bv = *(const float4*)(bt + c4);
            const float4 q0 = *(const float4*)(q + m0 * D_ + c4);
            const float4 q1 = *(const float4*)(q + m1 * D_ + c4);
            float4 g0, g1;
            g0.x = q0.x * gv.x; g0.y = q0.y * gv.y; g0.z = q0.z * gv.z; g0.w = q0.w * gv.w;
            g1.x = q1.x * gv.x; g1.y = q1.y * gv.y; g1.z = q1.z * gv.z; g1.w = q1.w * gv.w;
            *(float4*)&qg_s[m0][c4] = g0;
            *(float4*)&qg_s[m1][c4] = g1;
            qgs0 += g0.x + g0.y + g0.z + g0.w;
            qgs1 += g1.x + g1.y + g1.z + g1.w;
            qb0  += q0.x * bv.x + q0.y * bv.y + q0.z * bv.z + q0.w * bv.w;
            qb1  += q1.x * bv.x + q1.y * bv.y + q1.z * bv.z + q1.w * bv.w;
        }
#pragma unroll
        for (int mask = 32; mask; mask >>= 1) {
            qgs0 += __shfl_xor(qgs0, mask, 64);
            qgs1 += __shfl_xor(qgs1, mask, 64);
            qb0  += __shfl_xor(qb0,  mask, 64);
            qb1  += __shfl_xor(qb1,  mask, 64);
        }
        if (lane == 0) {
            qgs_s[m0] = qgs0; qgs_s[m1] = qgs1;
            qb_s[m0]  = qb0;  qb_s[m1]  = qb1;
        }
    }
    __syncthreads();

    const int mo = lane >> 3;
    const float qgs_sel = qgs_s[mo];
    const float qbs     = SCALE_ * qb_s[mo];

    const bool hi32 = (lane & 32) != 0;
    const bool hi16 = (lane & 16) != 0;
    const bool hi8  = (lane & 8)  != 0;

    const int gw = blockIdx.x * 4 + wv;            // 0..4095

    // 8 row-pairs per wave: pr = gw + it*4096, rows (2*pr, 2*pr+1) — same b always.
#pragma unroll 1
    for (int it = 0; it < 8; ++it) {
        const int pr   = gw + (it << 12);
        const int row0 = pr * 2;
        const float* xr0 = x + (size_t)row0 * D_;

        float v0[12], v1[12];
#pragma unroll
        for (int i = 0; i < 3; i++) {
            const int c4 = (lane + i * 64) * 4;
            const float4 p0 = *(const float4*)(xr0 + c4);
            const float4 p1 = *(const float4*)(xr0 + D_ + c4);
            v0[i * 4 + 0] = p0.x; v0[i * 4 + 1] = p0.y; v0[i * 4 + 2] = p0.z; v0[i * 4 + 3] = p0.w;
            v1[i * 4 + 0] = p1.x; v1[i * 4 + 1] = p1.y; v1[i * 4 + 2] = p1.z; v1[i * 4 + 3] = p1.w;
        }

        float s0 = 0.f, s20 = 0.f, s1 = 0.f, s21 = 0.f;
#pragma unroll
        for (int k = 0; k < 12; k++) {
            s0 += v0[k]; s20 += v0[k] * v0[k];
            s1 += v1[k]; s21 += v1[k] * v1[k];
        }

        float acc0[8], acc1[8];
#pragma unroll
        for (int m = 0; m < 8; m++) { acc0[m] = 0.f; acc1[m] = 0.f; }
#pragma unroll
        for (int i = 0; i < 3; i++) {
            const int c4 = (lane + i * 64) * 4;
#pragma unroll
            for (int m = 0; m < 8; m++) {
                const float4 qv = *(const float4*)&qg_s[m][c4];   // one read, two rows
                acc0[m] = fmaf(qv.x, v0[i * 4 + 0], acc0[m]);
                acc0[m] = fmaf(qv.y, v0[i * 4 + 1], acc0[m]);
                acc0[m] = fmaf(qv.z, v0[i * 4 + 2], acc0[m]);
                acc0[m] = fmaf(qv.w, v0[i * 4 + 3], acc0[m]);
                acc1[m] = fmaf(qv.x, v1[i * 4 + 0], acc1[m]);
                acc1[m] = fmaf(qv.y, v1[i * 4 + 1], acc1[m]);
                acc1[m] = fmaf(qv.z, v1[i * 4 + 2], acc1[m]);
                acc1[m] = fmaf(qv.w, v1[i * 4 + 3], acc1[m]);
            }
        }

        // stats: full butterflies, two rows interleaved (independent chains)
#pragma unroll
        for (int mask = 32; mask; mask >>= 1) {
            s0  += __shfl_xor(s0,  mask, 64);
            s1  += __shfl_xor(s1,  mask, 64);
            s20 += __shfl_xor(s20, mask, 64);
            s21 += __shfl_xor(s21, mask, 64);
        }
        const float mean0 = s0 * (1.0f / 768.0f);
        const float mean1 = s1 * (1.0f / 768.0f);
        float var0 = fmaxf(s20 * (1.0f / 768.0f) - mean0 * mean0, 0.0f);
        float var1 = fmaxf(s21 * (1.0f / 768.0f) - mean1 * mean1, 0.0f);
        const float rstd0 = rsqrtf(var0 + EPS_);
        const float rstd1 = rsqrtf(var1 + EPS_);

        // dot thinning for row0
        float a0 = hi32 ? acc0[4] : acc0[0], sA0 = hi32 ? acc0[0] : acc0[4];
        float a1 = hi32 ? acc0[5] : acc0[1], sA1 = hi32 ? acc0[1] : acc0[5];
        float a2 = hi32 ? acc0[6] : acc0[2], sA2 = hi32 ? acc0[2] : acc0[6];
        float a3 = hi32 ? acc0[7] : acc0[3], sA3 = hi32 ? acc0[3] : acc0[7];
        // and row1 (interleaved for ILP)
        float e0 = hi32 ? acc1[4] : acc1[0], sE0 = hi32 ? acc1[0] : acc1[4];
        float e1 = hi32 ? acc1[5] : acc1[1], sE1 = hi32 ? acc1[1] : acc1[5];
        float e2 = hi32 ? acc1[6] : acc1[2], sE2 = hi32 ? acc1[2] : acc1[6];
        float e3 = hi32 ? acc1[7] : acc1[3], sE3 = hi32 ? acc1[3] : acc1[7];
        a0 += __shfl_xor(sA0, 32, 64);  e0 += __shfl_xor(sE0, 32, 64);
        a1 += __shfl_xor(sA1, 32, 64);  e1 += __shfl_xor(sE1, 32, 64);
        a2 += __shfl_xor(sA2, 32, 64);  e2 += __shfl_xor(sE2, 32, 64);
        a3 += __shfl_xor(sA3, 32, 64);  e3 += __shfl_xor(sE3, 32, 64);
        float b0 = hi16 ? a2 : a0, sB0 = hi16 ? a0 : a2;
        float b1 = hi16 ? a3 : a1, sB1 = hi16 ? a1 : a3;
        float f0 = hi16 ? e2 : e0, sF0 = hi16 ? e0 : e2;
        float f1 = hi16 ? e3 : e1, sF1 = hi16 ? e1 : e3;
        b0 += __shfl_xor(sB0, 16, 64);  f0 += __shfl_xor(sF0, 16, 64);
        b1 += __shfl_xor(sB1, 16, 64);  f1 += __shfl_xor(sF1, 16, 64);
        float c0 = hi8 ? b1 : b0, sC0 = hi8 ? b0 : b1;
        float g0 = hi8 ? f1 : f0, sG0 = hi8 ? f0 : f1;
        c0 += __shfl_xor(sC0, 8, 64);   g0 += __shfl_xor(sG0, 8, 64);
        c0 += __shfl_xor(c0, 4, 64);    g0 += __shfl_xor(g0, 4, 64);
        c0 += __shfl_xor(c0, 2, 64);    g0 += __shfl_xor(g0, 2, 64);
        c0 += __shfl_xor(c0, 1, 64);    g0 += __shfl_xor(g0, 1, 64);

        const int b = row0 >> 12, n0 = row0 & (N_ - 1);
        if (lane == 0) {
            meanb[row0]     = mean0;  rstdb[row0]     = rstd0;
            meanb[row0 + 1] = mean1;  rstdb[row0 + 1] = rstd1;
        }
        if ((lane & 7) == 0) {
            float* sp = sim + (size_t)((b * 8 + mo) << 12) + n0;
            sp[0] = fmaf(rstd0 * SCALE_, c0 - mean0 * qgs_sel, qbs);
            sp[1] = fmaf(rstd1 * SCALE_, g0 - mean1 * qgs_sel, qbs);
        }
    }
}

// ---------------- kernel 2: softmax stats + w materialization + out init ----------------
// computes mx, 1/sum, wmu = sum_n attn*rstd*mu; writes w[bm][n] = attn*rstd;
// initializes out[b,m,d] = beta[d] - gamma[d]*wmu  (exact: softmax rows sum to 1)
__global__ __launch_bounds__(256) void k_stats(
    const float* __restrict__ sim,
    const float* __restrict__ meanb,
    const float* __restrict__ rstdb,
    const float* __restrict__ gm,
    const float* __restrict__ bt,
    float* __restrict__ wbuf,
    float* __restrict__ out)
{
    const int bm = blockIdx.x;            // b*8 + m, 0..127
    const int b  = bm >> 3;
    const float* p  = sim   + ((size_t)bm << 12);
    const float* mu = meanb + ((size_t)b  << 12);
    const float* rs = rstdb + ((size_t)b  << 12);
    const int t = threadIdx.x;
    const int lane = t & 63, wave = t >> 6;
    __shared__ float red[8];

    float v[16];
    float mx = -3.4e38f;
#pragma unroll
    for (int i = 0; i < 16; i++) { v[i] = p[t + i * 256]; mx = fmaxf(mx, v[i]); }
#pragma unroll
    for (int mask = 32; mask; mask >>= 1) mx = fmaxf(mx, __shfl_xor(mx, mask, 64));
    if (lane == 0) red[wave] = mx;
    __syncthreads();
    mx = fmaxf(fmaxf(red[0], red[1]), fmaxf(red[2], red[3]));
    __syncthreads();

    float rsv[16];
    float s = 0.f, smu = 0.f;
#pragma unroll
    for (int i = 0; i < 16; i++) {
        const int n = t + i * 256;
        const float e = __expf(v[i] - mx);
        rsv[i] = rs[n];
        s += e;
        smu = fmaf(e, rsv[i] * mu[n], smu);
        v[i] = e;                        // keep e for the w write
    }
#pragma unroll
    for (int mask = 32; mask; mask >>= 1) {
        s   += __shfl_xor(s,   mask, 64);
        smu += __shfl_xor(smu, mask, 64);
    }
    if (lane == 0) { red[wave] = s; red[wave + 4] = smu; }
    __syncthreads();
    s   = red[0] + red[1] + red[2] + red[3];
    smu = red[4] + red[5] + red[6] + red[7];
    const float inv = 1.0f / s;
    const float wmu = smu * inv;

    // materialize w = attn * rstd
    float* wrow = wbuf + ((size_t)bm << 12);
#pragma unroll
    for (int i = 0; i < 16; i++)
        wrow[t + i * 256] = v[i] * inv * rsv[i];

    // init this (b,m) output row: beta - gamma*wmu
    float* o = out + (size_t)bm * D_;
#pragma unroll
    for (int k = 0; k < 3; k++) {
        const int d = t + k * 256;
        o[d] = fmaf(-gm[d], wmu, bt[d]);
    }
}

// ---------------- kernel 3: out += g_d * sum_n w_mn * x_nd ----------------
// grid (16 b, 3 dchunk, 32 nchunk) = 1536 blocks (6/CU). Thread owns ONE
// column d = dc*256+t. w read at block-uniform addresses (scalar-load
// eligible; no LDS, no syncthreads, no exp). Inner loop: 1 x-load + 8 FMA
// per row. Atomics: 8/thread (3.1M, 16-way per address, m-rotated).
__global__ __launch_bounds__(256) void k_out(
    const float* __restrict__ x,
    const float* __restrict__ gm,
    const float* __restrict__ wbuf,
    float* __restrict__ out)
{
    const int b  = blockIdx.x;
    const int dc = blockIdx.y;
    const int nc = blockIdx.z;
    const int t  = threadIdx.x;
    const int n0 = nc << 7;                     // 128 rows per block
    const int d  = (dc << 8) + t;

    const float* wr = wbuf + ((size_t)(b << 3) << 12) + n0;   // + m*4096 + nn
    const float* xp = x + ((size_t)(b * N_ + n0)) * D_ + d;

    float acc[8];
#pragma unroll
    for (int m = 0; m < 8; m++) acc[m] = 0.f;

#pragma unroll 2
    for (int nn = 0; nn < 128; nn += 4) {
        const float x0 = xp[(size_t)(nn + 0) * D_];
        const float x1 = xp[(size_t)(nn + 1) * D_];
        const float x2 = xp[(size_t)(nn + 2) * D_];
        const float x3 = xp[(size_t)(nn + 3) * D_];
#pragma unroll
        for (int m = 0; m < 8; m++) {
            const float4 wq = *(const float4*)(wr + ((size_t)m << 12) + nn);  // uniform
            acc[m] = fmaf(wq.x, x0, acc[m]);
            acc[m] = fmaf(wq.y, x1, acc[m]);
            acc[m] = fmaf(wq.z, x2, acc[m]);
            acc[m] = fmaf(wq.w, x3, acc[m]);
        }
    }

    const float g = gm[d];
#pragma unroll
    for (int mm = 0; mm < 8; mm++) {
        const int m = (mm + nc) & 7;    // rotate to spread atomic contention
        atomicAdd(out + (size_t)((b << 3) + m) * D_ + d, g * acc[m]);
    }
}

extern "C" void kernel_launch(void* const* d_in, const int* in_sizes, int n_in,
                              void* d_out, int out_size, void* d_ws, size_t ws_size,
                              hipStream_t stream)
{
    const float* x  = (const float*)d_in[0];
    const float* q  = (const float*)d_in[1];
    const float* gm = (const float*)d_in[2];
    const float* bt = (const float*)d_in[3];
    float* out = (float*)d_out;

    float* ws    = (float*)d_ws;
    float* sim   = ws + SIM_OFF;
    float* meanb = ws + MEAN_OFF;
    float* rstdb = ws + RSTD_OFF;
    float* wbuf  = ws + WBUF_OFF;

    k_ln_sim<<<1024, 256, 0, stream>>>(x, q, gm, bt, sim, meanb, rstdb);
    k_stats<<<B_ * M_, 256, 0, stream>>>(sim, meanb, rstdb, gm, bt, wbuf, out);
    k_out<<<dim3(16, 3, 32), 256, 0, stream>>>(x, gm, wbuf, out);
}

// Round 4
// 317.144 us; speedup vs baseline: 1.0471x; 1.0471x over previous
//
#include <hip/hip_runtime.h>
#include <hip/hip_bf16.h>

// Problem: B=16, N=4096, D=768, M=8
//   xn = LayerNorm(x) * gamma + beta          [B,N,D]
//   sim = (queries @ xn^T) * D^-0.5           [B,M,N]
//   attn = softmax(sim, axis=-1)
//   out = attn @ xn                           [B,M,D]
// All I/O fp32. Compute fp32.
//
// Round-4: REVERT to the session-best round-2 configuration (316.7 us).
// Round-3's two changes (k_out uniform-VMEM w reads; 2-row k_ln_sim)
// regressed ~15 us combined and are dropped. Session conclusion: timed
// region = ~236 us harness ws-repoison fills (2 x 768 MiB @ ~117 us,
// dominating every rocprof top-5) + ~80 us kernels vs ~70 us composed
// memory floor (x read twice at 6.8 TB/s + stats + launch gaps).

#define B_ 16
#define N_ 4096
#define D_ 768
#define M_ 8
#define EPS_ 1e-3f
#define SCALE_ 0.03608439182435161f  // 768^-0.5

// ws layout (floats)
#define SIM_OFF   0            // B*M*N = 524288 floats
#define MEAN_OFF  524288       // B*N   =  65536
#define RSTD_OFF  589824       // B*N   =  65536
#define SMAX_OFF  655360       // B*M   =    128
#define SINV_OFF  655488       // B*M   =    128

// ---------------- kernel 1: LayerNorm stats + sim = q . xn ----------------
// one wave per row; lane owns 12 cols (3 float4).
// gamma folded into q: sim_m = SCALE*(rs*(dot(qg,v) - mu*qgs_m) + qb_m)
// qg table lives in LDS (block-shared), freeing ~96 VGPRs -> high occupancy.
__global__ __launch_bounds__(256) void k_ln_sim(
    const float* __restrict__ x,
    const float* __restrict__ q,
    const float* __restrict__ gm,
    const float* __restrict__ bt,
    float* __restrict__ sim, float* __restrict__ meanb, float* __restrict__ rstdb)
{
    __shared__ __align__(16) float qg_s[8][768];   // 24 KB
    __shared__ float qgs_s[8], qb_s[8];

    const int lane = threadIdx.x & 63;
    const int wv   = threadIdx.x >> 6;             // 0..3
    const int gw   = blockIdx.x * 4 + wv;
    const int total_waves = gridDim.x * 4;

    // ---- init: wave wv prepares m0=2wv, m1=2wv+1 (each wave's lanes cover all 768 cols)
    {
        const int m0 = wv * 2, m1 = m0 + 1;
        float qgs0 = 0.f, qb0 = 0.f, qgs1 = 0.f, qb1 = 0.f;
#pragma unroll
        for (int i = 0; i < 3; i++) {
            const int c4 = (lane + i * 64) * 4;
            const float4 gv = *(const float4*)(gm + c4);
            const float4 bv = *(const float4*)(bt + c4);
            const float4 q0 = *(const float4*)(q + m0 * D_ + c4);
            const float4 q1 = *(const float4*)(q + m1 * D_ + c4);
            float4 g0, g1;
            g0.x = q0.x * gv.x; g0.y = q0.y * gv.y; g0.z = q0.z * gv.z; g0.w = q0.w * gv.w;
            g1.x = q1.x * gv.x; g1.y = q1.y * gv.y; g1.z = q1.z * gv.z; g1.w = q1.w * gv.w;
            *(float4*)&qg_s[m0][c4] = g0;
            *(float4*)&qg_s[m1][c4] = g1;
            qgs0 += g0.x + g0.y + g0.z + g0.w;
            qgs1 += g1.x + g1.y + g1.z + g1.w;
            qb0  += q0.x * bv.x + q0.y * bv.y + q0.z * bv.z + q0.w * bv.w;
            qb1  += q1.x * bv.x + q1.y * bv.y + q1.z * bv.z + q1.w * bv.w;
        }
#pragma unroll
        for (int mask = 32; mask; mask >>= 1) {
            qgs0 += __shfl_xor(qgs0, mask, 64);
            qgs1 += __shfl_xor(qgs1, mask, 64);
            qb0  += __shfl_xor(qb0,  mask, 64);
            qb1  += __shfl_xor(qb1,  mask, 64);
        }
        if (lane == 0) {
            qgs_s[m0] = qgs0; qgs_s[m1] = qgs1;
            qb_s[m0]  = qb0;  qb_s[m1]  = qb1;
        }
    }
    __syncthreads();

    const int mo = lane >> 3;
    const float qgs_sel = qgs_s[mo];
    const float qbs     = SCALE_ * qb_s[mo];

    const bool hi32 = (lane & 32) != 0;
    const bool hi16 = (lane & 16) != 0;
    const bool hi8  = (lane & 8)  != 0;

    for (int row = gw; row < B_ * N_; row += total_waves) {
        const float* xr = x + (size_t)row * D_;
        float v[12];
#pragma unroll
        for (int i = 0; i < 3; i++) {
            float4 p = *(const float4*)(xr + (lane + i * 64) * 4);
            v[i * 4 + 0] = p.x; v[i * 4 + 1] = p.y;
            v[i * 4 + 2] = p.z; v[i * 4 + 3] = p.w;
        }
        // stats partials — independent of the dot chain
        float s = 0.f, s2 = 0.f;
#pragma unroll
        for (int k = 0; k < 12; k++) { s += v[k]; s2 += v[k] * v[k]; }

        float acc[8];
#pragma unroll
        for (int m = 0; m < 8; m++) acc[m] = 0.f;
#pragma unroll
        for (int i = 0; i < 3; i++) {
            const int c4 = (lane + i * 64) * 4;
#pragma unroll
            for (int m = 0; m < 8; m++) {
                const float4 qv = *(const float4*)&qg_s[m][c4];   // ds_read_b128
                acc[m] = fmaf(qv.x, v[i * 4 + 0], acc[m]);
                acc[m] = fmaf(qv.y, v[i * 4 + 1], acc[m]);
                acc[m] = fmaf(qv.z, v[i * 4 + 2], acc[m]);
                acc[m] = fmaf(qv.w, v[i * 4 + 3], acc[m]);
            }
        }

        // stats: full butterfly (all lanes need mean/rstd)
#pragma unroll
        for (int mask = 32; mask; mask >>= 1) {
            s  += __shfl_xor(s,  mask, 64);
            s2 += __shfl_xor(s2, mask, 64);
        }
        const float mean = s * (1.0f / 768.0f);
        float var = s2 * (1.0f / 768.0f) - mean * mean;
        var = fmaxf(var, 0.0f);
        const float rstd = rsqrtf(var + EPS_);

        // dot: thinning reduction, 8 values -> lane octet (lane>>3)==m
        float a0 = hi32 ? acc[4] : acc[0], sA0 = hi32 ? acc[0] : acc[4];
        float a1 = hi32 ? acc[5] : acc[1], sA1 = hi32 ? acc[1] : acc[5];
        float a2 = hi32 ? acc[6] : acc[2], sA2 = hi32 ? acc[2] : acc[6];
        float a3 = hi32 ? acc[7] : acc[3], sA3 = hi32 ? acc[3] : acc[7];
        a0 += __shfl_xor(sA0, 32, 64);
        a1 += __shfl_xor(sA1, 32, 64);
        a2 += __shfl_xor(sA2, 32, 64);
        a3 += __shfl_xor(sA3, 32, 64);
        float b0 = hi16 ? a2 : a0, sB0 = hi16 ? a0 : a2;
        float b1 = hi16 ? a3 : a1, sB1 = hi16 ? a1 : a3;
        b0 += __shfl_xor(sB0, 16, 64);
        b1 += __shfl_xor(sB1, 16, 64);
        float c0 = hi8 ? b1 : b0, sC0 = hi8 ? b0 : b1;
        c0 += __shfl_xor(sC0, 8, 64);
        c0 += __shfl_xor(c0, 4, 64);
        c0 += __shfl_xor(c0, 2, 64);
        c0 += __shfl_xor(c0, 1, 64);

        const int b = row >> 12, n = row & (N_ - 1);
        if (lane == 0) {
            meanb[row] = mean;
            rstdb[row] = rstd;
        }
        if ((lane & 7) == 0) {
            // sim = SCALE*(rs*(c0 - mu*qgs) + qb)
            sim[(size_t)((b * 8 + mo) << 12) + n] =
                fmaf(rstd * SCALE_, c0 - mean * qgs_sel, qbs);
        }
    }
}

// ---------------- kernel 2: per-(b,m) softmax stats + out row init ----------------
// computes mx, 1/sum, and wmu = sum_n attn_mn * rstd_n * mu_n.
// initializes out[b,m,d] = beta[d] - gamma[d]*wmu  (exact: softmax rows sum to 1)
__global__ __launch_bounds__(256) void k_stats(
    const float* __restrict__ sim,
    const float* __restrict__ meanb,
    const float* __restrict__ rstdb,
    const float* __restrict__ gm,
    const float* __restrict__ bt,
    float* __restrict__ smax, float* __restrict__ sinv,
    float* __restrict__ out)
{
    const int bm = blockIdx.x;            // b*8 + m, 0..127
    const int b  = bm >> 3;
    const float* p  = sim   + ((size_t)bm << 12);
    const float* mu = meanb + ((size_t)b  << 12);
    const float* rs = rstdb + ((size_t)b  << 12);
    const int t = threadIdx.x;
    const int lane = t & 63, wave = t >> 6;
    __shared__ float red[8];

    float v[16];
    float mx = -3.4e38f;
#pragma unroll
    for (int i = 0; i < 16; i++) { v[i] = p[t + i * 256]; mx = fmaxf(mx, v[i]); }
#pragma unroll
    for (int mask = 32; mask; mask >>= 1) mx = fmaxf(mx, __shfl_xor(mx, mask, 64));
    if (lane == 0) red[wave] = mx;
    __syncthreads();
    mx = fmaxf(fmaxf(red[0], red[1]), fmaxf(red[2], red[3]));
    __syncthreads();

    float s = 0.f, smu = 0.f;
#pragma unroll
    for (int i = 0; i < 16; i++) {
        const int n = t + i * 256;
        const float e = __expf(v[i] - mx);
        s += e;
        smu = fmaf(e, rs[n] * mu[n], smu);
    }
#pragma unroll
    for (int mask = 32; mask; mask >>= 1) {
        s   += __shfl_xor(s,   mask, 64);
        smu += __shfl_xor(smu, mask, 64);
    }
    if (lane == 0) { red[wave] = s; red[wave + 4] = smu; }
    __syncthreads();
    s   = red[0] + red[1] + red[2] + red[3];
    smu = red[4] + red[5] + red[6] + red[7];
    const float inv = 1.0f / s;
    const float wmu = smu * inv;
    if (t == 0) { smax[bm] = mx; sinv[bm] = inv; }

    // init this (b,m) output row: beta - gamma*wmu
    float* o = out + (size_t)bm * D_;
#pragma unroll
    for (int k = 0; k < 3; k++) {
        const int d = t + k * 256;
        o[d] = fmaf(-gm[d], wmu, bt[d]);
    }
}

// ---------------- kernel 3: out += g_d * sum_n w_mn * x_nd ----------------
// grid (16 b, 3 dchunk, 16 nchunk) = 768 blocks (3/CU). Thread owns ONE
// column d = dc*256+t; w[8][256] staged in LDS (broadcast float4 reads).
// Inner loop: 1 global load + 8 FMA per row. Atomics: 8 per thread
// (1.57M total, 16-way per address, m-rotated by nchunk).
__global__ __launch_bounds__(256) void k_out(
    const float* __restrict__ x,
    const float* __restrict__ gm,
    const float* __restrict__ sim,
    const float* __restrict__ rstdb,
    const float* __restrict__ smax,
    const float* __restrict__ sinv,
    float* __restrict__ out)
{
    __shared__ __align__(16) float w_s[8 * 256];   // [m][nn], 8 KB

    const int b  = blockIdx.x;
    const int dc = blockIdx.y;
    const int nc = blockIdx.z;
    const int t  = threadIdx.x;
    const int n0 = nc << 8;
    const int d  = (dc << 8) + t;

    // stage w[m][nn] = exp(sim - mx) * sinv * rstd
    const float rs_t = rstdb[((size_t)b << 12) + n0 + t];
#pragma unroll
    for (int m = 0; m < 8; m++) {
        const int bm = (b << 3) + m;
        const float v = sim[((size_t)bm << 12) + n0 + t];
        w_s[(m << 8) + t] = __expf(v - smax[bm]) * sinv[bm] * rs_t;
    }
    __syncthreads();

    float acc[8];
#pragma unroll
    for (int m = 0; m < 8; m++) acc[m] = 0.f;

    const float* xp = x + ((size_t)(b * N_ + n0)) * D_ + d;
#pragma unroll 2
    for (int nn = 0; nn < 256; nn += 4) {
        const float x0 = xp[(size_t)(nn + 0) * D_];
        const float x1 = xp[(size_t)(nn + 1) * D_];
        const float x2 = xp[(size_t)(nn + 2) * D_];
        const float x3 = xp[(size_t)(nn + 3) * D_];
#pragma unroll
        for (int m = 0; m < 8; m++) {
            const float4 wv = *(const float4*)&w_s[(m << 8) + nn];
            acc[m] = fmaf(wv.x, x0, acc[m]);
            acc[m] = fmaf(wv.y, x1, acc[m]);
            acc[m] = fmaf(wv.z, x2, acc[m]);
            acc[m] = fmaf(wv.w, x3, acc[m]);
        }
    }

    const float g = gm[d];
#pragma unroll
    for (int mm = 0; mm < 8; mm++) {
        const int m = (mm + nc) & 7;    // rotate to spread atomic contention
        atomicAdd(out + (size_t)((b << 3) + m) * D_ + d, g * acc[m]);
    }
}

extern "C" void kernel_launch(void* const* d_in, const int* in_sizes, int n_in,
                              void* d_out, int out_size, void* d_ws, size_t ws_size,
                              hipStream_t stream)
{
    const float* x  = (const float*)d_in[0];
    const float* q  = (const float*)d_in[1];
    const float* gm = (const float*)d_in[2];
    const float* bt = (const float*)d_in[3];
    float* out = (float*)d_out;

    float* ws    = (float*)d_ws;
    float* sim   = ws + SIM_OFF;
    float* meanb = ws + MEAN_OFF;
    float* rstdb = ws + RSTD_OFF;
    float* smax  = ws + SMAX_OFF;
    float* sinv  = ws + SINV_OFF;

    k_ln_sim<<<1536, 256, 0, stream>>>(x, q, gm, bt, sim, meanb, rstdb);
    k_stats<<<B_ * M_, 256, 0, stream>>>(sim, meanb, rstdb, gm, bt, smax, sinv, out);
    k_out<<<dim3(16, 3, 16), 256, 0, stream>>>(x, gm, sim, rstdb, smax, sinv, out);
}